// Round 1
// baseline (2084.426 us; speedup 1.0000x reference)
//
#include <hip/hip_runtime.h>
#include <math.h>

// fp32 baseline: 5 GEMMs + softmax.
// GEMM tile: 128x128, BK=16, 256 threads (16x16), 8x8 micro-tile per thread.
// A is [M][K] row-major. B is [N][K] (BTRANS=true, C=A*B^T) or [K][N] (false).

#define BM 128
#define BN 128
#define BKK 16

template<bool BTRANS>
__global__ __launch_bounds__(256)
void gemm_kernel(const float* __restrict__ A, const float* __restrict__ Bm,
                 const float* __restrict__ bias, float* __restrict__ C,
                 int M, int N, int K,
                 long strideA, long strideB, long strideC,
                 float scale)
{
    __shared__ float As[BKK][BM];
    __shared__ float Bs[BKK][BN];

    const int tid = threadIdx.x;
    const int tx = tid & 15;
    const int ty = tid >> 4;
    const int n0 = blockIdx.x * BN;
    const int m0 = blockIdx.y * BM;
    const int b  = blockIdx.z;

    const float* Ab = A + (long)b * strideA;
    const float* Bb = Bm + (long)b * strideB;
    float*       Cb = C + (long)b * strideC;

    float acc[8][8];
#pragma unroll
    for (int i = 0; i < 8; ++i)
#pragma unroll
        for (int j = 0; j < 8; ++j) acc[i][j] = 0.f;

    for (int k0 = 0; k0 < K; k0 += BKK) {
        __syncthreads();
        // stage A tile (transposed into As[k][m]); 128 rows x 16 k = 512 float4
#pragma unroll
        for (int l = 0; l < 2; ++l) {
            int f4 = tid + l * 256;          // 0..511
            int m  = f4 >> 2;                // 0..127
            int kc = (f4 & 3) * 4;           // 0,4,8,12
            float4 v = *reinterpret_cast<const float4*>(Ab + (long)(m0 + m) * K + k0 + kc);
            As[kc + 0][m] = v.x; As[kc + 1][m] = v.y;
            As[kc + 2][m] = v.z; As[kc + 3][m] = v.w;
        }
        if constexpr (BTRANS) {
#pragma unroll
            for (int l = 0; l < 2; ++l) {
                int f4 = tid + l * 256;
                int n  = f4 >> 2;
                int kc = (f4 & 3) * 4;
                float4 v = *reinterpret_cast<const float4*>(Bb + (long)(n0 + n) * K + k0 + kc);
                Bs[kc + 0][n] = v.x; Bs[kc + 1][n] = v.y;
                Bs[kc + 2][n] = v.z; Bs[kc + 3][n] = v.w;
            }
        } else {
#pragma unroll
            for (int l = 0; l < 2; ++l) {
                int f4 = tid + l * 256;
                int kk = f4 >> 5;            // 0..15
                int nc = (f4 & 31) * 4;      // 0..124
                float4 v = *reinterpret_cast<const float4*>(Bb + (long)(k0 + kk) * N + n0 + nc);
                *reinterpret_cast<float4*>(&Bs[kk][nc]) = v;
            }
        }
        __syncthreads();

#pragma unroll
        for (int kk = 0; kk < BKK; ++kk) {
            float a[8], bv[8];
            *reinterpret_cast<float4*>(&a[0]) = *reinterpret_cast<const float4*>(&As[kk][ty * 8]);
            *reinterpret_cast<float4*>(&a[4]) = *reinterpret_cast<const float4*>(&As[kk][ty * 8 + 4]);
            *reinterpret_cast<float4*>(&bv[0]) = *reinterpret_cast<const float4*>(&Bs[kk][tx * 8]);
            *reinterpret_cast<float4*>(&bv[4]) = *reinterpret_cast<const float4*>(&Bs[kk][tx * 8 + 4]);
#pragma unroll
            for (int i = 0; i < 8; ++i)
#pragma unroll
                for (int j = 0; j < 8; ++j)
                    acc[i][j] = fmaf(a[i], bv[j], acc[i][j]);
        }
    }

    // epilogue
#pragma unroll
    for (int i = 0; i < 8; ++i) {
        long row = m0 + ty * 8 + i;
        float o[8];
#pragma unroll
        for (int j = 0; j < 8; ++j) {
            int col = n0 + tx * 8 + j;
            float bb = bias ? bias[col] : 0.f;
            o[j] = acc[i][j] * scale + bb;
        }
        *reinterpret_cast<float4*>(Cb + row * N + n0 + tx * 8)     = *reinterpret_cast<float4*>(&o[0]);
        *reinterpret_cast<float4*>(Cb + row * N + n0 + tx * 8 + 4) = *reinterpret_cast<float4*>(&o[4]);
    }
}

// one block per row of 1024 scores; 256 threads x 4 elements
__global__ __launch_bounds__(256)
void softmax_kernel(float* __restrict__ S)
{
    long row = blockIdx.x;
    float* p = S + row * 1024;
    int tid = threadIdx.x;
    float4 v = *reinterpret_cast<float4*>(&p[tid * 4]);
    float m = fmaxf(fmaxf(v.x, v.y), fmaxf(v.z, v.w));
#pragma unroll
    for (int off = 1; off < 64; off <<= 1) m = fmaxf(m, __shfl_xor(m, off));
    __shared__ float redm[4];
    int wave = tid >> 6, lane = tid & 63;
    if (lane == 0) redm[wave] = m;
    __syncthreads();
    m = fmaxf(fmaxf(redm[0], redm[1]), fmaxf(redm[2], redm[3]));

    float e0 = expf(v.x - m), e1 = expf(v.y - m), e2 = expf(v.z - m), e3 = expf(v.w - m);
    float s = e0 + e1 + e2 + e3;
#pragma unroll
    for (int off = 1; off < 64; off <<= 1) s += __shfl_xor(s, off);
    __shared__ float reds[4];
    if (lane == 0) reds[wave] = s;
    __syncthreads();
    s = reds[0] + reds[1] + reds[2] + reds[3];
    float inv = 1.f / s;
    float4 o;
    o.x = e0 * inv; o.y = e1 * inv; o.z = e2 * inv; o.w = e3 * inv;
    *reinterpret_cast<float4*>(&p[tid * 4]) = o;
}

extern "C" void kernel_launch(void* const* d_in, const int* in_sizes, int n_in,
                              void* d_out, int out_size, void* d_ws, size_t ws_size,
                              hipStream_t stream)
{
    const float* query  = (const float*)d_in[0];
    const float* keys   = (const float*)d_in[1];
    const float* values = (const float*)d_in[2];
    const float* Wq     = (const float*)d_in[3];
    const float* bq     = (const float*)d_in[4];
    const float* Wk     = (const float*)d_in[5];
    const float* bk     = (const float*)d_in[6];
    const float* Wo     = (const float*)d_in[7];
    const float* bo     = (const float*)d_in[8];
    float* out = (float*)d_out;

    const int  Bb = 16, T = 1024, H = 1024;
    const long MT = (long)Bb * T;            // 16384

    size_t need = (size_t)(MT * H /*q*/ + MT * H /*k*/ + (long)Bb * T * T /*scores*/) * sizeof(float);
    if (ws_size < need) return;  // scratch too small: bail (will fail validation loudly)

    float* q   = (float*)d_ws;
    float* k   = q + MT * H;
    float* sc  = k + MT * H;
    float* ctx = q;                          // q is dead after the scores GEMM

    dim3 blk(256);

    // 1. q = query @ Wq^T + bq
    gemm_kernel<true><<<dim3(H / BN, MT / BM, 1), blk, 0, stream>>>(
        query, Wq, bq, q, (int)MT, H, H, 0, 0, 0, 1.f);
    // 2. k = keys @ Wk^T + bk
    gemm_kernel<true><<<dim3(H / BN, MT / BM, 1), blk, 0, stream>>>(
        keys, Wk, bk, k, (int)MT, H, H, 0, 0, 0, 1.f);
    // 3. scores = q @ k^T  (batched over B)
    gemm_kernel<true><<<dim3(T / BN, T / BM, Bb), blk, 0, stream>>>(
        q, k, nullptr, sc, T, T, H, (long)T * H, (long)T * H, (long)T * T, 1.f);
    // 4. softmax rows
    softmax_kernel<<<dim3((unsigned)MT), blk, 0, stream>>>(sc);
    // 5. ctx = attn @ values / 32   (batched)
    gemm_kernel<false><<<dim3(H / BN, T / BM, Bb), blk, 0, stream>>>(
        sc, values, nullptr, ctx, T, H, T, (long)T * T, (long)T * H, (long)T * H, 1.f / 32.f);
    // 6. out = ctx @ Wo^T + bo
    gemm_kernel<true><<<dim3(H / BN, MT / BM, 1), blk, 0, stream>>>(
        ctx, Wo, bo, out, (int)MT, H, H, 0, 0, 0, 1.f);
}

// Round 2
// 601.642 us; speedup vs baseline: 3.4646x; 3.4646x over previous
//
#include <hip/hip_runtime.h>
#include <math.h>

typedef __attribute__((ext_vector_type(4))) float f32x4;
typedef __attribute__((ext_vector_type(8))) short s16x8;
typedef __attribute__((ext_vector_type(4))) short s16x4;

__device__ inline unsigned short f2bf(float f) {
    union { float f; unsigned int u; } v; v.f = f;
    unsigned int u = v.u;
    return (unsigned short)((u + 0x7FFFu + ((u >> 16) & 1u)) >> 16);
}
__device__ inline float bf2f(unsigned short h) {
    union { unsigned int u; float f; } v; v.u = ((unsigned int)h) << 16;
    return v.f;
}

__device__ inline void async16(const void* g, void* l) {
    __builtin_amdgcn_global_load_lds(
        (const __attribute__((address_space(1))) unsigned int*)g,
        (__attribute__((address_space(3))) unsigned int*)l,
        16, 0, 0);
}

#define TM 128
#define TN 128
#define TK 32

// C[M][N] = scale * (A[M][K] . B[N][K]^T) + bias
// AM/BM_: 0 = fp32 source, on-the-fly hi/lo split (A only)
//         1 = pre-split bf16 pair (ptr0 = hi, ptr1 = lo)
//         2 = plain bf16
// OM: 0 = fp32 out (+bias), 1 = split bf16 pair out (+bias), 2 = bf16 out
template<int AM, int BMODE, int OM>
__global__ __launch_bounds__(256)
void mfma_gemm(const void* A0, const void* A1,
               const void* B0, const void* B1,
               const float* __restrict__ bias,
               void* C0, void* C1,
               int N, int K,
               long sA, long sB, long sC, float scale)
{
    __shared__ unsigned short Ah[TM * TK];
    __shared__ unsigned short Bh[TM * TK];
    __shared__ unsigned short Al[(AM == 2) ? 16 : TM * TK];
    __shared__ unsigned short Bl[(BMODE == 2) ? 16 : TM * TK];

    const int tid  = threadIdx.x;
    const int wave = tid >> 6;
    const int lane = tid & 63;
    const int wr = wave >> 1, wc = wave & 1;
    const int n0 = blockIdx.x * TN;
    const int m0 = blockIdx.y * TM;
    const long b = blockIdx.z;

    const int lrow = lane & 15;        // fragment row/col within 16
    const int lk   = (lane >> 4) * 8;  // fragment k offset (elements)

    f32x4 zero = {0.f, 0.f, 0.f, 0.f};
    f32x4 acc[4][4];
#pragma unroll
    for (int i = 0; i < 4; ++i)
#pragma unroll
        for (int j = 0; j < 4; ++j) acc[i][j] = zero;

    for (int k0 = 0; k0 < K; k0 += TK) {
        __syncthreads();
        // ---------------- stage A ----------------
        if constexpr (AM == 0) {
            const float* Ag = (const float*)A0 + b * sA;
#pragma unroll
            for (int l = 0; l < 4; ++l) {
                int f4  = l * 256 + tid;       // 1024 float4 chunks
                int row = f4 >> 3;
                int kc  = (f4 & 7) * 4;
                float4 v = *(const float4*)(Ag + (long)(m0 + row) * K + k0 + kc);
                unsigned short h0 = f2bf(v.x), h1 = f2bf(v.y), h2 = f2bf(v.z), h3 = f2bf(v.w);
                s16x4 hv = {(short)h0, (short)h1, (short)h2, (short)h3};
                s16x4 lv = {(short)f2bf(v.x - bf2f(h0)), (short)f2bf(v.y - bf2f(h1)),
                            (short)f2bf(v.z - bf2f(h2)), (short)f2bf(v.w - bf2f(h3))};
                *(s16x4*)&Ah[row * TK + kc] = hv;
                *(s16x4*)&Al[row * TK + kc] = lv;
            }
        } else {
            const unsigned short* Ag = (const unsigned short*)A0 + b * sA;
#pragma unroll
            for (int l = 0; l < 2; ++l) {
                int i16 = l * 256 + tid;       // 512 16B chunks
                int row = i16 >> 2;
                int kc  = (i16 & 3) * 8;
                async16(Ag + (long)(m0 + row) * K + k0 + kc,
                        &Ah[(l * 256 + wave * 64) * 8]);
            }
            if constexpr (AM == 1) {
                const unsigned short* Ag2 = (const unsigned short*)A1 + b * sA;
#pragma unroll
                for (int l = 0; l < 2; ++l) {
                    int i16 = l * 256 + tid;
                    int row = i16 >> 2;
                    int kc  = (i16 & 3) * 8;
                    async16(Ag2 + (long)(m0 + row) * K + k0 + kc,
                            &Al[(l * 256 + wave * 64) * 8]);
                }
            }
        }
        // ---------------- stage B ----------------
        {
            const unsigned short* Bg = (const unsigned short*)B0 + b * sB;
#pragma unroll
            for (int l = 0; l < 2; ++l) {
                int i16 = l * 256 + tid;
                int row = i16 >> 2;
                int kc  = (i16 & 3) * 8;
                async16(Bg + (long)(n0 + row) * K + k0 + kc,
                        &Bh[(l * 256 + wave * 64) * 8]);
            }
            if constexpr (BMODE == 1) {
                const unsigned short* Bg2 = (const unsigned short*)B1 + b * sB;
#pragma unroll
                for (int l = 0; l < 2; ++l) {
                    int i16 = l * 256 + tid;
                    int row = i16 >> 2;
                    int kc  = (i16 & 3) * 8;
                    async16(Bg2 + (long)(n0 + row) * K + k0 + kc,
                            &Bl[(l * 256 + wave * 64) * 8]);
                }
            }
        }
        __syncthreads();

        // ---------------- fragments + MFMA ----------------
        s16x8 a_h[4], b_h[4];
#pragma unroll
        for (int f = 0; f < 4; ++f) {
            a_h[f] = *(const s16x8*)&Ah[(wr * 64 + f * 16 + lrow) * TK + lk];
            b_h[f] = *(const s16x8*)&Bh[(wc * 64 + f * 16 + lrow) * TK + lk];
        }
#pragma unroll
        for (int i = 0; i < 4; ++i)
#pragma unroll
            for (int j = 0; j < 4; ++j)
                acc[i][j] = __builtin_amdgcn_mfma_f32_16x16x32_bf16(a_h[i], b_h[j], acc[i][j], 0, 0, 0);

        if constexpr (AM != 2) {   // A-lo pass
            s16x8 a_l[4];
#pragma unroll
            for (int f = 0; f < 4; ++f)
                a_l[f] = *(const s16x8*)&Al[(wr * 64 + f * 16 + lrow) * TK + lk];
#pragma unroll
            for (int i = 0; i < 4; ++i)
#pragma unroll
                for (int j = 0; j < 4; ++j)
                    acc[i][j] = __builtin_amdgcn_mfma_f32_16x16x32_bf16(a_l[i], b_h[j], acc[i][j], 0, 0, 0);
        }
        if constexpr (BMODE != 2) {  // B-lo pass
            s16x8 b_l[4];
#pragma unroll
            for (int f = 0; f < 4; ++f)
                b_l[f] = *(const s16x8*)&Bl[(wc * 64 + f * 16 + lrow) * TK + lk];
#pragma unroll
            for (int i = 0; i < 4; ++i)
#pragma unroll
                for (int j = 0; j < 4; ++j)
                    acc[i][j] = __builtin_amdgcn_mfma_f32_16x16x32_bf16(a_h[i], b_l[j], acc[i][j], 0, 0, 0);
        }
    }

    // ---------------- epilogue ----------------
#pragma unroll
    for (int j = 0; j < 4; ++j) {
        int col = n0 + wc * 64 + j * 16 + lrow;
        float bb = bias ? bias[col] : 0.f;
#pragma unroll
        for (int i = 0; i < 4; ++i) {
#pragma unroll
            for (int r = 0; r < 4; ++r) {
                long row = m0 + wr * 64 + i * 16 + (lane >> 4) * 4 + r;
                float v = acc[i][j][r] * scale + bb;
                long idx = b * sC + row * (long)N + col;
                if constexpr (OM == 0) {
                    ((float*)C0)[idx] = v;
                } else if constexpr (OM == 1) {
                    unsigned short h = f2bf(v);
                    ((unsigned short*)C0)[idx] = h;
                    ((unsigned short*)C1)[idx] = f2bf(v - bf2f(h));
                } else {
                    ((unsigned short*)C0)[idx] = f2bf(v);
                }
            }
        }
    }
}

// fp32 -> bf16 hi/lo split, 4 elems/thread
__global__ __launch_bounds__(256)
void split_f32(const float* __restrict__ in, unsigned short* __restrict__ hi,
               unsigned short* __restrict__ lo, int n)
{
    int i = (blockIdx.x * 256 + threadIdx.x) * 4;
    if (i >= n) return;
    float4 v = *(const float4*)(in + i);
    unsigned short h0 = f2bf(v.x), h1 = f2bf(v.y), h2 = f2bf(v.z), h3 = f2bf(v.w);
    s16x4 hv = {(short)h0, (short)h1, (short)h2, (short)h3};
    s16x4 lv = {(short)f2bf(v.x - bf2f(h0)), (short)f2bf(v.y - bf2f(h1)),
                (short)f2bf(v.z - bf2f(h2)), (short)f2bf(v.w - bf2f(h3))};
    *(s16x4*)(hi + i) = hv;
    *(s16x4*)(lo + i) = lv;
}

__global__ __launch_bounds__(256)
void conv_f32(const float* __restrict__ in, unsigned short* __restrict__ out, int n)
{
    int i = (blockIdx.x * 256 + threadIdx.x) * 4;
    if (i >= n) return;
    float4 v = *(const float4*)(in + i);
    s16x4 hv = {(short)f2bf(v.x), (short)f2bf(v.y), (short)f2bf(v.z), (short)f2bf(v.w)};
    *(s16x4*)(out + i) = hv;
}

// values [16][1024][1024] f32 -> vT [16][1024][1024] bf16 (per-batch transpose)
__global__ __launch_bounds__(256)
void transpose_conv(const float* __restrict__ in, unsigned short* __restrict__ out)
{
    __shared__ float tile[32][33];
    const long base = (long)blockIdx.z * 1024 * 1024;
    const int h0 = blockIdx.x * 32, t0 = blockIdx.y * 32;
    for (int i = threadIdx.y; i < 32; i += 8)
        tile[i][threadIdx.x] = in[base + (long)(t0 + i) * 1024 + h0 + threadIdx.x];
    __syncthreads();
    for (int i = threadIdx.y; i < 32; i += 8)
        out[base + (long)(h0 + i) * 1024 + t0 + threadIdx.x] = f2bf(tile[threadIdx.x][i]);
}

// row softmax: fp32 scores (1024/row) -> bf16 probs
__global__ __launch_bounds__(256)
void softmax_bf16(const float* __restrict__ S, unsigned short* __restrict__ P)
{
    long row = blockIdx.x;
    const int tid = threadIdx.x;
    float4 v = *(const float4*)(S + row * 1024 + tid * 4);
    float m = fmaxf(fmaxf(v.x, v.y), fmaxf(v.z, v.w));
#pragma unroll
    for (int off = 1; off < 64; off <<= 1) m = fmaxf(m, __shfl_xor(m, off));
    __shared__ float redm[4];
    int wave = tid >> 6, lane = tid & 63;
    if (lane == 0) redm[wave] = m;
    __syncthreads();
    m = fmaxf(fmaxf(redm[0], redm[1]), fmaxf(redm[2], redm[3]));

    float e0 = expf(v.x - m), e1 = expf(v.y - m), e2 = expf(v.z - m), e3 = expf(v.w - m);
    float s = e0 + e1 + e2 + e3;
#pragma unroll
    for (int off = 1; off < 64; off <<= 1) s += __shfl_xor(s, off);
    __shared__ float reds[4];
    if (lane == 0) reds[wave] = s;
    __syncthreads();
    s = reds[0] + reds[1] + reds[2] + reds[3];
    float inv = 1.f / s;
    s16x4 o = {(short)f2bf(e0 * inv), (short)f2bf(e1 * inv),
               (short)f2bf(e2 * inv), (short)f2bf(e3 * inv)};
    *(s16x4*)(P + row * 1024 + tid * 4) = o;
}

extern "C" void kernel_launch(void* const* d_in, const int* in_sizes, int n_in,
                              void* d_out, int out_size, void* d_ws, size_t ws_size,
                              hipStream_t stream)
{
    const float* query  = (const float*)d_in[0];
    const float* keys   = (const float*)d_in[1];
    const float* values = (const float*)d_in[2];
    const float* Wq     = (const float*)d_in[3];
    const float* bq     = (const float*)d_in[4];
    const float* Wk     = (const float*)d_in[5];
    const float* bk     = (const float*)d_in[6];
    const float* Wo     = (const float*)d_in[7];
    const float* bo     = (const float*)d_in[8];

    const int  T = 1024, H = 1024;
    const long NE = 16384L * 1024;   // B*T*H
    const long NW = 1024L * 1024;    // H*H

    size_t need = (size_t)(NE * 5 + NW * 5) * sizeof(unsigned short);
    if (ws_size < need) return;

    unsigned short* ws  = (unsigned short*)d_ws;
    unsigned short* qh  = ws;
    unsigned short* ql  = qh + NE;
    unsigned short* kh  = ql + NE;
    unsigned short* kl  = kh + NE;
    unsigned short* vT  = kl + NE;
    unsigned short* Wqh = vT + NE;
    unsigned short* Wql = Wqh + NW;
    unsigned short* Wkh = Wql + NW;
    unsigned short* Wkl = Wkh + NW;
    unsigned short* Wob = Wkl + NW;
    unsigned short* attn = qh;       // dead after scores GEMM
    unsigned short* ctx  = ql;       // dead after scores GEMM
    float* scores = (float*)d_out;   // d_out doubles as scratch; overwritten by stage 6

    // weight prep + value transpose
    split_f32<<<1024, 256, 0, stream>>>(Wq, Wqh, Wql, (int)NW);
    split_f32<<<1024, 256, 0, stream>>>(Wk, Wkh, Wkl, (int)NW);
    conv_f32<<<1024, 256, 0, stream>>>(Wo, Wob, (int)NW);
    transpose_conv<<<dim3(32, 32, 16), dim3(32, 8), 0, stream>>>(values, vT);

    // 1. q = query @ Wq^T + bq  (split out)
    mfma_gemm<0, 1, 1><<<dim3(8, 128, 1), 256, 0, stream>>>(
        query, nullptr, Wqh, Wql, bq, qh, ql, H, H, 0, 0, 0, 1.f);
    // 2. k = keys @ Wk^T + bk
    mfma_gemm<0, 1, 1><<<dim3(8, 128, 1), 256, 0, stream>>>(
        keys, nullptr, Wkh, Wkl, bk, kh, kl, H, H, 0, 0, 0, 1.f);
    // 3. scores = q @ k^T (batched, fp32 out to d_out)
    mfma_gemm<1, 1, 0><<<dim3(8, 8, 16), 256, 0, stream>>>(
        qh, ql, kh, kl, nullptr, scores, nullptr, T, H,
        (long)T * H, (long)T * H, (long)T * T, 1.f);
    // 4. softmax -> bf16 attn
    softmax_bf16<<<16384, 256, 0, stream>>>(scores, attn);
    // 5. ctx = attn @ vT^T / 32 (batched, bf16 out)
    mfma_gemm<2, 2, 2><<<dim3(8, 8, 16), 256, 0, stream>>>(
        attn, nullptr, vT, nullptr, nullptr, ctx, nullptr, H, T,
        (long)T * T, (long)T * H, (long)T * H, 1.f / 32.f);
    // 6. out = ctx @ Wo^T + bo (fp32 out)
    mfma_gemm<2, 2, 0><<<dim3(8, 128, 1), 256, 0, stream>>>(
        ctx, nullptr, Wob, nullptr, bo, d_out, nullptr, H, H, 0, 0, 0, 1.f);
}

// Round 3
// 435.205 us; speedup vs baseline: 4.7895x; 1.3824x over previous
//
#include <hip/hip_runtime.h>
#include <math.h>

typedef __attribute__((ext_vector_type(4))) float f32x4;
typedef __attribute__((ext_vector_type(8))) _Float16 h16x8;
typedef __attribute__((ext_vector_type(4))) short s16x4;

__device__ inline unsigned short f2h(float f) {
    union { _Float16 h; unsigned short u; } v;
    v.h = (_Float16)f;
    return v.u;
}

__device__ inline void async16(const void* g, void* l) {
    __builtin_amdgcn_global_load_lds(
        (const __attribute__((address_space(1))) unsigned int*)g,
        (__attribute__((address_space(3))) unsigned int*)l,
        16, 0, 0);
}

#define TM 128
#define TN 128
#define TK 32

// C[M][N] = scale * (A[M][K] . B[N][K]^T) + bias ; A,B fp16, fp32 accum.
// OM: 0 = fp32 out, 1 = fp16 out
template<int OM>
__global__ __launch_bounds__(256)
void mfma_gemm_f16(const unsigned short* __restrict__ A,
                   const unsigned short* __restrict__ B,
                   const float* __restrict__ bias,
                   void* C, int N, int K,
                   long sA, long sB, long sC, float scale)
{
    __shared__ unsigned short Ah[TM * TK];
    __shared__ unsigned short Bh[TM * TK];

    const int tid  = threadIdx.x;
    const int wave = tid >> 6;
    const int lane = tid & 63;
    const int wr = wave >> 1, wc = wave & 1;
    const int n0 = blockIdx.x * TN;
    const int m0 = blockIdx.y * TM;
    const long b = blockIdx.z;

    const int lrow = lane & 15;
    const int lk   = (lane >> 4) * 8;

    const unsigned short* Ag = A + b * sA;
    const unsigned short* Bg = B + b * sB;

    f32x4 zero = {0.f, 0.f, 0.f, 0.f};
    f32x4 acc[4][4];
#pragma unroll
    for (int i = 0; i < 4; ++i)
#pragma unroll
        for (int j = 0; j < 4; ++j) acc[i][j] = zero;

    for (int k0 = 0; k0 < K; k0 += TK) {
        __syncthreads();
#pragma unroll
        for (int l = 0; l < 2; ++l) {
            int i16 = l * 256 + tid;          // 512 16B chunks per operand tile
            int row = i16 >> 2;
            int kc  = (i16 & 3) * 8;
            async16(Ag + (long)(m0 + row) * K + k0 + kc,
                    &Ah[(l * 256 + wave * 64) * 8]);
        }
#pragma unroll
        for (int l = 0; l < 2; ++l) {
            int i16 = l * 256 + tid;
            int row = i16 >> 2;
            int kc  = (i16 & 3) * 8;
            async16(Bg + (long)(n0 + row) * K + k0 + kc,
                    &Bh[(l * 256 + wave * 64) * 8]);
        }
        __syncthreads();

        h16x8 a_f[4], b_f[4];
#pragma unroll
        for (int f = 0; f < 4; ++f) {
            a_f[f] = *(const h16x8*)&Ah[(wr * 64 + f * 16 + lrow) * TK + lk];
            b_f[f] = *(const h16x8*)&Bh[(wc * 64 + f * 16 + lrow) * TK + lk];
        }
#pragma unroll
        for (int i = 0; i < 4; ++i)
#pragma unroll
            for (int j = 0; j < 4; ++j)
                acc[i][j] = __builtin_amdgcn_mfma_f32_16x16x32_f16(a_f[i], b_f[j], acc[i][j], 0, 0, 0);
    }

#pragma unroll
    for (int j = 0; j < 4; ++j) {
        int col = n0 + wc * 64 + j * 16 + lrow;
        float bb = bias ? bias[col] : 0.f;
#pragma unroll
        for (int i = 0; i < 4; ++i) {
#pragma unroll
            for (int r = 0; r < 4; ++r) {
                long row = m0 + wr * 64 + i * 16 + (lane >> 4) * 4 + r;
                float v = acc[i][j][r] * scale + bb;
                long idx = b * sC + row * (long)N + col;
                if constexpr (OM == 0) ((float*)C)[idx] = v;
                else                   ((unsigned short*)C)[idx] = f2h(v);
            }
        }
    }
}

// fp32 -> fp16 conversion, 4 elems/thread
__global__ __launch_bounds__(256)
void conv_f16(const float* __restrict__ in, unsigned short* __restrict__ out, int n)
{
    int i = (blockIdx.x * 256 + threadIdx.x) * 4;
    if (i >= n) return;
    float4 v = *(const float4*)(in + i);
    s16x4 o = {(short)f2h(v.x), (short)f2h(v.y), (short)f2h(v.z), (short)f2h(v.w)};
    *(s16x4*)(out + i) = o;
}

// values [16][1024][1024] f32 -> vT [16][1024][1024] fp16 (per-batch transpose)
__global__ __launch_bounds__(256)
void transpose_f16(const float* __restrict__ in, unsigned short* __restrict__ out)
{
    __shared__ float tile[32][33];
    const long base = (long)blockIdx.z * 1024 * 1024;
    const int h0 = blockIdx.x * 32, t0 = blockIdx.y * 32;
    for (int i = threadIdx.y; i < 32; i += 8)
        tile[i][threadIdx.x] = in[base + (long)(t0 + i) * 1024 + h0 + threadIdx.x];
    __syncthreads();
    for (int i = threadIdx.y; i < 32; i += 8)
        out[base + (long)(h0 + i) * 1024 + t0 + threadIdx.x] = f2h(tile[threadIdx.x][i]);
}

// row softmax: fp32 scores (1024/row) -> fp16 probs
__global__ __launch_bounds__(256)
void softmax_f16(const float* __restrict__ S, unsigned short* __restrict__ P)
{
    long row = blockIdx.x;
    const int tid = threadIdx.x;
    float4 v = *(const float4*)(S + row * 1024 + tid * 4);
    float m = fmaxf(fmaxf(v.x, v.y), fmaxf(v.z, v.w));
#pragma unroll
    for (int off = 1; off < 64; off <<= 1) m = fmaxf(m, __shfl_xor(m, off));
    __shared__ float redm[4];
    int wave = tid >> 6, lane = tid & 63;
    if (lane == 0) redm[wave] = m;
    __syncthreads();
    m = fmaxf(fmaxf(redm[0], redm[1]), fmaxf(redm[2], redm[3]));

    float e0 = expf(v.x - m), e1 = expf(v.y - m), e2 = expf(v.z - m), e3 = expf(v.w - m);
    float s = e0 + e1 + e2 + e3;
#pragma unroll
    for (int off = 1; off < 64; off <<= 1) s += __shfl_xor(s, off);
    __shared__ float reds[4];
    if (lane == 0) reds[wave] = s;
    __syncthreads();
    s = reds[0] + reds[1] + reds[2] + reds[3];
    float inv = 1.f / s;
    s16x4 o = {(short)f2h(e0 * inv), (short)f2h(e1 * inv),
               (short)f2h(e2 * inv), (short)f2h(e3 * inv)};
    *(s16x4*)(P + row * 1024 + tid * 4) = o;
}

extern "C" void kernel_launch(void* const* d_in, const int* in_sizes, int n_in,
                              void* d_out, int out_size, void* d_ws, size_t ws_size,
                              hipStream_t stream)
{
    const float* query  = (const float*)d_in[0];
    const float* keys   = (const float*)d_in[1];
    const float* values = (const float*)d_in[2];
    const float* Wq     = (const float*)d_in[3];
    const float* bq     = (const float*)d_in[4];
    const float* Wk     = (const float*)d_in[5];
    const float* bk     = (const float*)d_in[6];
    const float* Wo     = (const float*)d_in[7];
    const float* bo     = (const float*)d_in[8];

    const int  T = 1024, H = 1024;
    const long NE = 16384L * 1024;   // B*T*H
    const long NW = 1024L * 1024;    // H*H

    size_t need = (size_t)(NE * 5 + NW * 3) * sizeof(unsigned short);
    if (ws_size < need) return;

    unsigned short* ws  = (unsigned short*)d_ws;
    unsigned short* Xq  = ws;             // query fp16   (dead after stage 1)
    unsigned short* Xk  = Xq + NE;        // keys fp16    (dead after stage 2)
    unsigned short* qf  = Xk + NE;
    unsigned short* kf  = qf + NE;
    unsigned short* vT  = kf + NE;
    unsigned short* Wqh = vT + NE;
    unsigned short* Wkh = Wqh + NW;
    unsigned short* Woh = Wkh + NW;
    unsigned short* attn = Xq;            // alias: probs
    unsigned short* ctx  = Xk;            // alias: context
    float* scores = (float*)d_out;        // d_out doubles as fp32 scratch

    // ---- prep: fp32 -> fp16 ----
    conv_f16<<<16384, 256, 0, stream>>>(query, Xq, (int)NE);
    conv_f16<<<16384, 256, 0, stream>>>(keys,  Xk, (int)NE);
    conv_f16<<<1024,  256, 0, stream>>>(Wq, Wqh, (int)NW);
    conv_f16<<<1024,  256, 0, stream>>>(Wk, Wkh, (int)NW);
    conv_f16<<<1024,  256, 0, stream>>>(Wo, Woh, (int)NW);
    transpose_f16<<<dim3(32, 32, 16), dim3(32, 8), 0, stream>>>(values, vT);

    // 1. q = query @ Wq^T + bq   (fp16 out)
    mfma_gemm_f16<1><<<dim3(8, 128, 1), 256, 0, stream>>>(
        Xq, Wqh, bq, qf, H, H, 0, 0, 0, 1.f);
    // 2. k = keys @ Wk^T + bk
    mfma_gemm_f16<1><<<dim3(8, 128, 1), 256, 0, stream>>>(
        Xk, Wkh, bk, kf, H, H, 0, 0, 0, 1.f);
    // 3. scores = q @ k^T (batched, fp32 out into d_out)
    mfma_gemm_f16<0><<<dim3(8, 8, 16), 256, 0, stream>>>(
        qf, kf, nullptr, scores, T, H, (long)T * H, (long)T * H, (long)T * T, 1.f);
    // 4. softmax -> fp16 probs
    softmax_f16<<<16384, 256, 0, stream>>>(scores, attn);
    // 5. ctx = attn @ vT^T / 32 (batched, fp16 out)
    mfma_gemm_f16<1><<<dim3(8, 8, 16), 256, 0, stream>>>(
        attn, vT, nullptr, ctx, H, T, (long)T * T, (long)T * H, (long)T * H, 1.f / 32.f);
    // 6. out = ctx @ Wo^T + bo (fp32 out)
    mfma_gemm_f16<0><<<dim3(8, 128, 1), 256, 0, stream>>>(
        ctx, Woh, bo, d_out, H, H, 0, 0, 0, 1.f);
}

// Round 4
// 317.520 us; speedup vs baseline: 6.5647x; 1.3706x over previous
//
#include <hip/hip_runtime.h>
#include <math.h>

typedef __attribute__((ext_vector_type(4))) float f32x4;
typedef __attribute__((ext_vector_type(8))) _Float16 h16x8;
typedef __attribute__((ext_vector_type(4))) short s16x4;

__device__ inline unsigned short f2h(float f) {
    union { _Float16 h; unsigned short u; } v; v.h = (_Float16)f; return v.u;
}

__device__ inline void async16(const void* g, void* l) {
    __builtin_amdgcn_global_load_lds(
        (const __attribute__((address_space(1))) unsigned int*)g,
        (__attribute__((address_space(3))) unsigned int*)l, 16, 0, 0);
}

#define BM 256
#define BN 256
#define BK 64
#define NTHREADS 512

// LDS map (bytes), 128 KiB total:
//   buf d in {0,1}: base = d*65536
//   A half h (h in {0,1}): d*65536 + h*16384        (128 rows x 64 f16, XOR-swizzled)
//   B half h:             d*65536 + 32768 + h*16384
// Swizzle (involution, 16B-granular): stored_off = row*128 + (cb ^ ((row&7)<<4))

// Stage one 128x64 f16 half-tile: 2 x global_load_lds(16B) per thread.
// LDS dest is linear (wave-uniform base + lane*16); the swizzle is applied as the
// (identical, involutive) permutation on the per-lane GLOBAL source address.
__device__ inline void stage_half(const unsigned short* g, int row0, int kel, int K,
                                  unsigned ldsbase, char* smem, int tid) {
    const int rl  = tid >> 3;                          // 0..63 row within 64-row group
    const int scb = ((tid & 7) ^ (rl & 7)) << 4;       // swizzled source column byte
    char* wb = smem + ldsbase + (unsigned)((tid >> 6) << 10);   // wave-uniform
#pragma unroll
    for (int s = 0; s < 2; ++s) {
        long off = ((long)(row0 + s * 64 + rl) * K + kel) * 2 + scb;
        async16((const char*)g + off, wb + s * 8192);
    }
}

__device__ inline h16x8 ld_frag(const char* smem, unsigned base, int row, int kbyte) {
    unsigned off = base + (unsigned)(row * 128) + (unsigned)(kbyte ^ ((row & 7) << 4));
    return *(const h16x8*)(smem + off);
}

// C[M][N] = scale*(A[M][K] . B[N][K]^T) + bias ; A,B fp16 row-major pitch K.
// OM: 0 = fp32 out, 1 = fp16 out. 8-phase 256^2 schedule (T2+T3+T4+T5).
template<int OM>
__global__ __launch_bounds__(NTHREADS, 2)
void gemm256(const unsigned short* __restrict__ A,
             const unsigned short* __restrict__ B,
             const float* __restrict__ bias,
             void* __restrict__ C, int N, int K,
             long sA, long sB, long sC, float scale)
{
    __shared__ __align__(16) char smem[131072];

    const int tid  = threadIdx.x;
    const int wv   = tid >> 6;
    const int lane = tid & 63;
    const int wr = wv >> 2, wc = wv & 3;       // 2M x 4N waves
    const int lrow = lane & 15;
    const int kq16 = (lane >> 4) * 16;         // k-quarter byte offset

    // bijective XCD-aware workgroup swizzle (m204 form)
    const long gx = gridDim.x, gy = gridDim.y;
    const long nwg = gx * gy * (long)gridDim.z;
    const long hw  = ((long)blockIdx.z * gy + blockIdx.y) * gx + blockIdx.x;
    const long qq = nwg >> 3, rr = nwg & 7;
    const long xcd = hw & 7, pos = hw >> 3;
    const long lg = (xcd < rr) ? xcd * (qq + 1) + pos
                               : rr * (qq + 1) + (xcd - rr) * qq + pos;
    const int bx = (int)(lg % gx);
    const long rem = lg / gx;
    const int by = (int)(rem % gy);
    const int bz = (int)(rem / gy);

    const int n0 = bx * BN;
    const int m0 = by * BM;

    const unsigned short* Ag = A + (long)bz * sA;
    const unsigned short* Bg = B + (long)bz * sB;

    const int NT = K / BK;   // even, >= 2

    auto stageA = [&](int t, int h) {
        stage_half(Ag, m0 + h * 128, t * BK, K,
                   (unsigned)(((t & 1) << 16) + (h << 14)), smem, tid);
    };
    auto stageB = [&](int t, int h) {
        stage_half(Bg, n0 + h * 128, t * BK, K,
                   (unsigned)(((t & 1) << 16) + 32768 + (h << 14)), smem, tid);
    };

    f32x4 acc[8][4];
#pragma unroll
    for (int i = 0; i < 8; ++i)
#pragma unroll
        for (int j = 0; j < 4; ++j) acc[i][j] = (f32x4){0.f, 0.f, 0.f, 0.f};

    const unsigned AbaseW = (unsigned)(wr * 16384);
    const unsigned BbaseW = (unsigned)(32768 + (wc >> 1) * 16384);
    const int brow0 = (wc & 1) * 64;

    // prologue: issue t0.B0,B1,A0,A1, t1.B0,B1 ; wait all but last 2 halves
    stageB(0, 0); stageB(0, 1); stageA(0, 0); stageA(0, 1); stageB(1, 0); stageB(1, 1);
    asm volatile("s_waitcnt vmcnt(4)" ::: "memory");
    __builtin_amdgcn_sched_barrier(0);
    __builtin_amdgcn_s_barrier();

    h16x8 bfr[4][2], afr[2][2];

    for (int i = 0; i < NT / 2; ++i) {
        const int t1 = 2 * i + 1, t2 = 2 * i + 2, t3 = 2 * i + 3;
        // ---------- phases 1-4: tile 2i from buf0 ----------
#pragma unroll
        for (int q = 0; q < 4; ++q) {
            if (q == 0) {
#pragma unroll
                for (int j = 0; j < 4; ++j)
#pragma unroll
                    for (int ks = 0; ks < 2; ++ks)
                        bfr[j][ks] = ld_frag(smem, BbaseW, brow0 + j * 16 + lrow, ks * 64 + kq16);
            }
#pragma unroll
            for (int f = 0; f < 2; ++f)
#pragma unroll
                for (int ks = 0; ks < 2; ++ks)
                    afr[f][ks] = ld_frag(smem, AbaseW, q * 32 + f * 16 + lrow, ks * 64 + kq16);
            // stage exactly 1 half-tile per phase (region dead since >=1 barrier)
            if (q == 0)      stageA(t1, 0);                 // buf1.A0 (read last: prev ph8)
            else if (q == 1) stageA(t1, 1);                 // buf1.A1
            else if (q == 2) { if (t2 < NT) stageB(t2, 0); } // buf0.B0 (read last: ph1)
            else             { if (t2 < NT) stageB(t2, 1); } // buf0.B1

            __builtin_amdgcn_s_barrier();
            asm volatile("s_waitcnt lgkmcnt(0)" ::: "memory");
            __builtin_amdgcn_sched_barrier(0);
            __builtin_amdgcn_s_setprio(1);
#pragma unroll
            for (int f = 0; f < 2; ++f)
#pragma unroll
                for (int j = 0; j < 4; ++j)
#pragma unroll
                    for (int ks = 0; ks < 2; ++ks)
                        acc[2 * q + f][j] = __builtin_amdgcn_mfma_f32_16x16x32_f16(
                            afr[f][ks], bfr[j][ks], acc[2 * q + f][j], 0, 0, 0);
            __builtin_amdgcn_s_setprio(0);
            if (q == 3) {
                if (t2 < NT) { asm volatile("s_waitcnt vmcnt(4)" ::: "memory"); }
                else         { asm volatile("s_waitcnt vmcnt(0)" ::: "memory"); }
                __builtin_amdgcn_sched_barrier(0);
            }
            __builtin_amdgcn_s_barrier();
        }
        // ---------- phases 5-8: tile 2i+1 from buf1 ----------
#pragma unroll
        for (int q = 0; q < 4; ++q) {
            if (q == 0) {
#pragma unroll
                for (int j = 0; j < 4; ++j)
#pragma unroll
                    for (int ks = 0; ks < 2; ++ks)
                        bfr[j][ks] = ld_frag(smem, 65536u + BbaseW, brow0 + j * 16 + lrow, ks * 64 + kq16);
            }
#pragma unroll
            for (int f = 0; f < 2; ++f)
#pragma unroll
                for (int ks = 0; ks < 2; ++ks)
                    afr[f][ks] = ld_frag(smem, 65536u + AbaseW, q * 32 + f * 16 + lrow, ks * 64 + kq16);
            if (q == 0)      { if (t2 < NT) stageA(t2, 0); } // buf0.A0 (read last: ph4)
            else if (q == 1) { if (t2 < NT) stageA(t2, 1); }
            else if (q == 2) { if (t3 < NT) stageB(t3, 0); } // buf1.B0 (read last: ph5)
            else             { if (t3 < NT) stageB(t3, 1); }

            __builtin_amdgcn_s_barrier();
            asm volatile("s_waitcnt lgkmcnt(0)" ::: "memory");
            __builtin_amdgcn_sched_barrier(0);
            __builtin_amdgcn_s_setprio(1);
#pragma unroll
            for (int f = 0; f < 2; ++f)
#pragma unroll
                for (int j = 0; j < 4; ++j)
#pragma unroll
                    for (int ks = 0; ks < 2; ++ks)
                        acc[2 * q + f][j] = __builtin_amdgcn_mfma_f32_16x16x32_f16(
                            afr[f][ks], bfr[j][ks], acc[2 * q + f][j], 0, 0, 0);
            __builtin_amdgcn_s_setprio(0);
            if (q == 3) {
                if (t3 < NT) { asm volatile("s_waitcnt vmcnt(4)" ::: "memory"); }
                else         { asm volatile("s_waitcnt vmcnt(0)" ::: "memory"); }
                __builtin_amdgcn_sched_barrier(0);
            }
            __builtin_amdgcn_s_barrier();
        }
    }

    // ---------------- epilogue ----------------
#pragma unroll
    for (int j = 0; j < 4; ++j) {
        const int col = n0 + wc * 64 + j * 16 + lrow;
        const float bb = bias ? bias[col] : 0.f;
#pragma unroll
        for (int mi = 0; mi < 8; ++mi) {
#pragma unroll
            for (int r = 0; r < 4; ++r) {
                const long row = m0 + wr * 128 + mi * 16 + (lane >> 4) * 4 + r;
                const float v = acc[mi][j][r] * scale + bb;
                const long idx = (long)bz * sC + row * (long)N + col;
                if constexpr (OM == 0) ((float*)C)[idx] = v;
                else                   ((unsigned short*)C)[idx] = f2h(v);
            }
        }
    }
}

// fp32 -> fp16 conversion, 4 elems/thread
__global__ __launch_bounds__(256)
void conv_f16(const float* __restrict__ in, unsigned short* __restrict__ out, int n)
{
    int i = (blockIdx.x * 256 + threadIdx.x) * 4;
    if (i >= n) return;
    float4 v = *(const float4*)(in + i);
    s16x4 o = {(short)f2h(v.x), (short)f2h(v.y), (short)f2h(v.z), (short)f2h(v.w)};
    *(s16x4*)(out + i) = o;
}

// values [16][1024][1024] f32 -> vT [16][1024][1024] fp16 (per-batch transpose)
__global__ __launch_bounds__(256)
void transpose_f16(const float* __restrict__ in, unsigned short* __restrict__ out)
{
    __shared__ float tile[32][33];
    const long base = (long)blockIdx.z * 1024 * 1024;
    const int h0 = blockIdx.x * 32, t0 = blockIdx.y * 32;
    for (int i = threadIdx.y; i < 32; i += 8)
        tile[i][threadIdx.x] = in[base + (long)(t0 + i) * 1024 + h0 + threadIdx.x];
    __syncthreads();
    for (int i = threadIdx.y; i < 32; i += 8)
        out[base + (long)(h0 + i) * 1024 + t0 + threadIdx.x] = f2h(tile[threadIdx.x][i]);
}

// row softmax: fp32 scores (1024/row) -> fp16 probs
__global__ __launch_bounds__(256)
void softmax_f16(const float* __restrict__ S, unsigned short* __restrict__ P)
{
    long row = blockIdx.x;
    const int tid = threadIdx.x;
    float4 v = *(const float4*)(S + row * 1024 + tid * 4);
    float m = fmaxf(fmaxf(v.x, v.y), fmaxf(v.z, v.w));
#pragma unroll
    for (int off = 1; off < 64; off <<= 1) m = fmaxf(m, __shfl_xor(m, off));
    __shared__ float redm[4];
    int wave = tid >> 6, lane = tid & 63;
    if (lane == 0) redm[wave] = m;
    __syncthreads();
    m = fmaxf(fmaxf(redm[0], redm[1]), fmaxf(redm[2], redm[3]));

    float e0 = expf(v.x - m), e1 = expf(v.y - m), e2 = expf(v.z - m), e3 = expf(v.w - m);
    float s = e0 + e1 + e2 + e3;
#pragma unroll
    for (int off = 1; off < 64; off <<= 1) s += __shfl_xor(s, off);
    __shared__ float reds[4];
    if (lane == 0) reds[wave] = s;
    __syncthreads();
    s = reds[0] + reds[1] + reds[2] + reds[3];
    float inv = 1.f / s;
    s16x4 o = {(short)f2h(e0 * inv), (short)f2h(e1 * inv),
               (short)f2h(e2 * inv), (short)f2h(e3 * inv)};
    *(s16x4*)(P + row * 1024 + tid * 4) = o;
}

extern "C" void kernel_launch(void* const* d_in, const int* in_sizes, int n_in,
                              void* d_out, int out_size, void* d_ws, size_t ws_size,
                              hipStream_t stream)
{
    const float* query  = (const float*)d_in[0];
    const float* keys   = (const float*)d_in[1];
    const float* values = (const float*)d_in[2];
    const float* Wq     = (const float*)d_in[3];
    const float* bq     = (const float*)d_in[4];
    const float* Wk     = (const float*)d_in[5];
    const float* bk     = (const float*)d_in[6];
    const float* Wo     = (const float*)d_in[7];
    const float* bo     = (const float*)d_in[8];

    const int  T = 1024, H = 1024;
    const long NE = 16384L * 1024;   // B*T*H
    const long NW = 1024L * 1024;    // H*H

    size_t need = (size_t)(NE * 5 + NW * 3) * sizeof(unsigned short);
    if (ws_size < need) return;

    unsigned short* ws  = (unsigned short*)d_ws;
    unsigned short* Xq  = ws;             // query fp16   (dead after stage 1)
    unsigned short* Xk  = Xq + NE;        // keys fp16    (dead after stage 2)
    unsigned short* qf  = Xk + NE;
    unsigned short* kf  = qf + NE;
    unsigned short* vT  = kf + NE;
    unsigned short* Wqh = vT + NE;
    unsigned short* Wkh = Wqh + NW;
    unsigned short* Woh = Wkh + NW;
    unsigned short* attn = Xq;            // alias: probs
    unsigned short* ctx  = Xk;            // alias: context
    float* scores = (float*)d_out;        // d_out doubles as fp32 scratch

    // ---- prep: fp32 -> fp16 ----
    conv_f16<<<16384, 256, 0, stream>>>(query, Xq, (int)NE);
    conv_f16<<<16384, 256, 0, stream>>>(keys,  Xk, (int)NE);
    conv_f16<<<1024,  256, 0, stream>>>(Wq, Wqh, (int)NW);
    conv_f16<<<1024,  256, 0, stream>>>(Wk, Wkh, (int)NW);
    conv_f16<<<1024,  256, 0, stream>>>(Wo, Woh, (int)NW);
    transpose_f16<<<dim3(32, 32, 16), dim3(32, 8), 0, stream>>>(values, vT);

    // 1. q = query @ Wq^T + bq   (fp16 out)   grid 4x64 = 256 WG
    gemm256<1><<<dim3(4, 64, 1), NTHREADS, 0, stream>>>(
        Xq, Wqh, bq, qf, H, H, 0, 0, 0, 1.f);
    // 2. k = keys @ Wk^T + bk
    gemm256<1><<<dim3(4, 64, 1), NTHREADS, 0, stream>>>(
        Xk, Wkh, bk, kf, H, H, 0, 0, 0, 1.f);
    // 3. scores = q @ k^T (batched, fp32 out into d_out)  grid 4x4x16 = 256 WG
    gemm256<0><<<dim3(4, 4, 16), NTHREADS, 0, stream>>>(
        qf, kf, nullptr, scores, T, H, (long)T * H, (long)T * H, (long)T * T, 1.f);
    // 4. softmax -> fp16 probs
    softmax_f16<<<16384, 256, 0, stream>>>(scores, attn);
    // 5. ctx = attn @ vT^T / 32 (batched, fp16 out)
    gemm256<1><<<dim3(4, 4, 16), NTHREADS, 0, stream>>>(
        attn, vT, nullptr, ctx, H, T, (long)T * T, (long)T * H, (long)T * H, 1.f / 32.f);
    // 6. out = ctx @ Wo^T + bo (fp32 out)
    gemm256<0><<<dim3(4, 64, 1), NTHREADS, 0, stream>>>(
        ctx, Woh, bo, d_out, H, H, 0, 0, 0, 1.f);
}